// Round 1
// baseline (30183.713 us; speedup 1.0000x reference)
//
#include <hip/hip_runtime.h>
#include <cstdint>
#include <cmath>

#define FEAT 256
#define GATES 1024
#define BS 64
#define SEQ 2048
#define NEG_BIG -10000.0f
#define MIN_SEG 3.0f

// ws layout in floats
#define WT_OFF   0                       // [256][1024]  W_hh^T
#define WIT_OFF  262144                  // [256][1024]  W_ih[:,1:]^T
#define WPB_OFF  524288                  // [1024]       W_ih[:,0]
#define BIAS_OFF 525312                  // [1024]       b_ih + b_hh
#define XP_OFF   526336                  // [2048][64][1024]  x-projection (+bias)
#define WS_FLOATS_MODE0 (XP_OFF + (size_t)SEQ * BS * GATES)

__global__ __launch_bounds__(1024) void prep_kernel(
    const float* __restrict__ W_ih, const float* __restrict__ W_hh,
    const float* __restrict__ b_ih, const float* __restrict__ b_hh,
    float* __restrict__ ws)
{
    const int k = blockIdx.x;    // 0..255
    const int j = threadIdx.x;   // 0..1023
    ws[WT_OFF  + k * GATES + j] = W_hh[(size_t)j * FEAT + k];
    ws[WIT_OFF + k * GATES + j] = W_ih[(size_t)j * (FEAT + 1) + 1 + k];
    if (k == 0) {
        ws[WPB_OFF  + j] = W_ih[(size_t)j * (FEAT + 1)];
        ws[BIAS_OFF + j] = b_ih[j] + b_hh[j];
    }
}

// XP[t][b][j] = sum_k x[b][t][k] * W_ih[j][k+1] + bias[j]
__global__ __launch_bounds__(256) void xproj_gemm(
    const float* __restrict__ x, const float* __restrict__ W_ih,
    const float* __restrict__ bias, float* __restrict__ XP)
{
    const int t  = blockIdx.y;
    const int j0 = blockIdx.x * 64;
    const int tid = threadIdx.x;
    const int ty = tid >> 4, tx = tid & 15;
    __shared__ __align__(16) float As[64][65];   // [b][k]
    __shared__ __align__(16) float Bs[64][65];   // [k][j]
    float acc[4][4] = {};
    for (int k0 = 0; k0 < FEAT; k0 += 64) {
#pragma unroll
        for (int i = 0; i < 16; ++i) {
            int idx = i * 256 + tid;
            int rr = idx >> 6, cc = idx & 63;            // rr=batch, cc=k
            As[rr][cc] = x[((size_t)rr * SEQ + t) * FEAT + k0 + cc];
        }
#pragma unroll
        for (int i = 0; i < 16; ++i) {
            int idx = i * 256 + tid;
            int jj = idx >> 6, kk = idx & 63;
            Bs[kk][jj] = W_ih[(size_t)(j0 + jj) * (FEAT + 1) + 1 + k0 + kk];
        }
        __syncthreads();
#pragma unroll
        for (int kk = 0; kk < 64; ++kk) {
            float a[4], bv[4];
#pragma unroll
            for (int r = 0; r < 4; ++r) a[r] = As[ty * 4 + r][kk];
#pragma unroll
            for (int c = 0; c < 4; ++c) bv[c] = Bs[kk][tx * 4 + c];
#pragma unroll
            for (int r = 0; r < 4; ++r)
#pragma unroll
                for (int c = 0; c < 4; ++c)
                    acc[r][c] = fmaf(a[r], bv[c], acc[r][c]);
        }
        __syncthreads();
    }
#pragma unroll
    for (int r = 0; r < 4; ++r) {
        int bb = ty * 4 + r;
        size_t base = ((size_t)t * BS + bb) * GATES + j0 + tx * 4;
        float4 v;
        v.x = acc[r][0] + bias[j0 + tx * 4 + 0];
        v.y = acc[r][1] + bias[j0 + tx * 4 + 1];
        v.z = acc[r][2] + bias[j0 + tx * 4 + 2];
        v.w = acc[r][3] + bias[j0 + tx * 4 + 3];
        *(float4*)&XP[base] = v;
    }
}

__device__ __forceinline__ float sigmoidf_(float v) { return 1.0f / (1.0f + expf(-v)); }

// MODE 0: x-projection precomputed in XP.  MODE 1: fused (stream WIT too).
template <int MODE>
__global__ __launch_bounds__(1024) void seq_kernel(
    const float* __restrict__ ws, const float* __restrict__ XP,
    const float* __restrict__ x,
    const float* __restrict__ Wp, const float* __restrict__ bp,
    float* __restrict__ out_b, float* __restrict__ out_sel)
{
    const int b   = blockIdx.x;
    const int tid = threadIdx.x;
    const int kc  = tid >> 8;      // 0..3  (k-chunk)
    const int jq  = tid & 255;     // 0..255
    const int j0  = jq * 4;

    __shared__ __align__(16) float h_lds[FEAT];
    __shared__ __align__(16) float x_s[FEAT];
    __shared__ __align__(16) float part[4][GATES];
    __shared__ float red[8];
    __shared__ float s_prev, s_flag;

    if (tid < FEAT) {
        h_lds[tid] = 0.0f;
        if (MODE == 1) x_s[tid] = x[((size_t)b * SEQ + 0) * FEAT + tid];
    }
    if (tid == 0) { s_prev = 0.0f; s_flag = 0.0f; }

    float c_reg = 0.0f;
    float wp0 = 0.f, wp1 = 0.f;
    float wpb_i = 0.f, wpb_f = 0.f, wpb_g = 0.f, wpb_o = 0.f;
    float bias_i = 0.f, bias_f = 0.f, bias_g = 0.f, bias_o = 0.f;
    if (tid < FEAT) {
        wp0 = Wp[tid]; wp1 = Wp[FEAT + tid];
        wpb_i = ws[WPB_OFF + tid];
        wpb_f = ws[WPB_OFF + 256 + tid];
        wpb_g = ws[WPB_OFF + 512 + tid];
        wpb_o = ws[WPB_OFF + 768 + tid];
        if (MODE == 1) {
            bias_i = ws[BIAS_OFF + tid];
            bias_f = ws[BIAS_OFF + 256 + tid];
            bias_g = ws[BIAS_OFF + 512 + tid];
            bias_o = ws[BIAS_OFF + 768 + tid];
        }
    }
    const float bp0 = bp[0], bp1 = bp[1];
    const float* WT  = ws + WT_OFF  + (size_t)(kc * 64) * GATES + j0;
    const float* WIT = ws + WIT_OFF + (size_t)(kc * 64) * GATES + j0;
    __syncthreads();

    for (int t = 0; t < SEQ; ++t) {
        // ---- phase 1: matvec partials over this thread's k-chunk ----
        float4 acc = make_float4(0.f, 0.f, 0.f, 0.f);
#pragma unroll 4
        for (int kk = 0; kk < 64; ++kk) {
            float hk = h_lds[kc * 64 + kk];
            float4 w = *(const float4*)(WT + kk * GATES);
            acc.x = fmaf(hk, w.x, acc.x);
            acc.y = fmaf(hk, w.y, acc.y);
            acc.z = fmaf(hk, w.z, acc.z);
            acc.w = fmaf(hk, w.w, acc.w);
            if (MODE == 1) {
                float xk = x_s[kc * 64 + kk];
                float4 wi = *(const float4*)(WIT + kk * GATES);
                acc.x = fmaf(xk, wi.x, acc.x);
                acc.y = fmaf(xk, wi.y, acc.y);
                acc.z = fmaf(xk, wi.z, acc.z);
                acc.w = fmaf(xk, wi.w, acc.w);
            }
        }
        *(float4*)&part[kc][j0] = acc;
        __syncthreads();   // A: partials visible; h/x reads of this step done

        // ---- phase 2: gate combine + LSTM update (threads 0..255) ----
        if (tid < FEAT) {
            const int k = tid;
            float prevb = s_prev;
            float gi = part[0][k]       + part[1][k]       + part[2][k]       + part[3][k];
            float gf = part[0][256 + k] + part[1][256 + k] + part[2][256 + k] + part[3][256 + k];
            float gg = part[0][512 + k] + part[1][512 + k] + part[2][512 + k] + part[3][512 + k];
            float go = part[0][768 + k] + part[1][768 + k] + part[2][768 + k] + part[3][768 + k];
            if (MODE == 0) {
                const float* xp = XP + ((size_t)t * BS + b) * GATES;
                gi += xp[k]; gf += xp[256 + k]; gg += xp[512 + k]; go += xp[768 + k];
            } else {
                gi += bias_i; gf += bias_f; gg += bias_g; go += bias_o;
            }
            gi = fmaf(prevb, wpb_i, gi);
            gf = fmaf(prevb, wpb_f, gf);
            gg = fmaf(prevb, wpb_g, gg);
            go = fmaf(prevb, wpb_o, go);
            float ig = sigmoidf_(gi);
            float fg = sigmoidf_(gf);
            float gt = tanhf(gg);
            float og = sigmoidf_(go);
            c_reg = fg * c_reg + ig * gt;
            float h = og * tanhf(c_reg);
            h_lds[k] = h;
            float p0 = h * wp0, p1 = h * wp1;
#pragma unroll
            for (int off = 32; off > 0; off >>= 1) {
                p0 += __shfl_down(p0, off);
                p1 += __shfl_down(p1, off);
            }
            if ((tid & 63) == 0) { red[tid >> 6] = p0; red[4 + (tid >> 6)] = p1; }
        } else if (MODE == 1 && tid < 512) {
            int k = tid - 256;
            int tn = t + 1;
            if (tn < SEQ) x_s[k] = x[((size_t)b * SEQ + tn) * FEAT + k];
        }
        __syncthreads();   // B: h_lds / red / x_s visible

        // ---- phase 3: decision (thread 0). No sync needed after: readers of
        // s_prev/s_flag (phase 2 of t+1) are ordered behind barrier A of t+1.
        if (tid == 0) {
            float l0 = red[0] + red[1] + red[2] + red[3] + bp0;
            float l1 = red[4] + red[5] + red[6] + red[7] + bp1;
            float flag = s_flag;
            if (flag > 0.0f) l1 += NEG_BIG;
            int samp = (l1 > l0) ? 1 : 0;
            float a0 = l0 * 0.5f, a1 = l1 * 0.5f;     // logits / TAU, TAU = 2
            float m = fmaxf(a0, a1);
            float lse = m + logf(expf(a0 - m) + expf(a1 - m));
            out_b[(size_t)b * SEQ + t]   = (float)samp;
            out_sel[(size_t)b * SEQ + t] = (samp ? a1 : a0) - lse;
            flag = (flag > 0.0f) ? (flag - 1.0f) : flag;
            if (samp) flag = MIN_SEG;
            s_flag = flag;
            s_prev = (float)samp;
        }
    }
}

extern "C" void kernel_launch(void* const* d_in, const int* in_sizes, int n_in,
                              void* d_out, int out_size, void* d_ws, size_t ws_size,
                              hipStream_t stream)
{
    const float* x    = (const float*)d_in[0];
    // d_in[1] = label (unused by the reference forward)
    const float* W_ih = (const float*)d_in[2];
    const float* W_hh = (const float*)d_in[3];
    const float* b_ih = (const float*)d_in[4];
    const float* b_hh = (const float*)d_in[5];
    const float* Wp   = (const float*)d_in[6];
    const float* bp   = (const float*)d_in[7];

    float* ws      = (float*)d_ws;
    float* out_b   = (float*)d_out;
    float* out_sel = out_b + (size_t)BS * SEQ;

    hipLaunchKernelGGL(prep_kernel, dim3(FEAT), dim3(GATES), 0, stream,
                       W_ih, W_hh, b_ih, b_hh, ws);

    const bool mode0 = ws_size >= WS_FLOATS_MODE0 * sizeof(float);
    if (mode0) {
        float* XP = ws + XP_OFF;
        hipLaunchKernelGGL(xproj_gemm, dim3(GATES / 64, SEQ), dim3(256), 0, stream,
                           x, W_ih, ws + BIAS_OFF, XP);
        hipLaunchKernelGGL((seq_kernel<0>), dim3(BS), dim3(1024), 0, stream,
                           ws, XP, x, Wp, bp, out_b, out_sel);
    } else {
        hipLaunchKernelGGL((seq_kernel<1>), dim3(BS), dim3(1024), 0, stream,
                           ws, (const float*)nullptr, x, Wp, bp, out_b, out_sel);
    }
}